// Round 1
// baseline (3097.608 us; speedup 1.0000x reference)
//
#include <hip/hip_runtime.h>

#define NN 1024
#define MM 1024
#define NBATCH 16
#define BIGF 1.0e10f

__device__ __forceinline__ float softmin3(float a, float b, float c) {
  float mn = fminf(a, fminf(b, c));
  float s = expf(mn - a) + expf(mn - b) + expf(mn - c);
  return mn - logf(s);
}

// D[b,i,j] = (x[b,i] - y[j])^2 ; coalesced float4 writes
__global__ __launch_bounds__(256) void d_init_kernel(const float* __restrict__ x,
                                                     const float* __restrict__ y,
                                                     float* __restrict__ D) {
  size_t idx = ((size_t)blockIdx.x * blockDim.x + threadIdx.x) * 4;
  int j = (int)(idx & (MM - 1));
  size_t bi = idx >> 10;  // / MM
  float xi = x[bi];
  const float4 yv = *reinterpret_cast<const float4*>(y + j);
  float t0 = xi - yv.x, t1 = xi - yv.y, t2 = xi - yv.z, t3 = xi - yv.w;
  float4 o;
  o.x = t0 * t0; o.y = t1 * t1; o.z = t2 * t2; o.w = t3 * t3;
  *reinterpret_cast<float4*>(D + idx) = o;
}

// R boundary: R[b,0,0]=0, R[b,0,j>=1]=BIG, R[b,i>=1,0]=BIG
__global__ __launch_bounds__(1024) void r_bound_kernel(float* __restrict__ R) {
  int b = blockIdx.x, t = threadIdx.x;
  float* Rb = R + (size_t)b * (NN + 1) * (MM + 1);
  Rb[t + 1] = BIGF;                       // row 0, j = 1..1024
  Rb[(size_t)(t + 1) * (MM + 1)] = BIGF;  // col 0, i = 1..1024
  if (t == 0) Rb[0] = 0.0f;
}

// Forward DP: one WG per batch, thread t owns row i=t+1, wavefront over diagonals.
__global__ __launch_bounds__(1024) void sdtw_fwd_kernel(const float* __restrict__ x,
                                                        const float* __restrict__ y,
                                                        float* __restrict__ R,
                                                        float* __restrict__ score) {
  __shared__ float rbuf[3][NN + 2];
  const int b = blockIdx.x, t = threadIdx.x;
  const int i = t + 1;
  float* Rb = R + (size_t)b * (NN + 1) * (MM + 1);
  const float xi = x[b * NN + t];  // x[b, i-1]
  // diag d=0: R[0,0]=0 at index 0, rest invalid(BIG). diag d=1: all BIG.
  rbuf[0][i] = BIGF;
  rbuf[1][i] = BIGF;
  if (t == 0) { rbuf[0][0] = 0.0f; rbuf[1][0] = BIGF; }
  __syncthreads();
  int c2 = 0, c1 = 1, c0 = 2;  // d-2, d-1, current
  float last_r = 0.0f;
  for (int d = 2; d <= NN + MM; ++d) {
    // valid: 1<=i<=N, 1<=j=d-i<=M  ->  d-M <= i <= d-1
    if (i >= d - MM && i <= d - 1) {
      const int j = d - i;
      float dv = xi - y[j - 1];
      dv *= dv;
      const float a = rbuf[c2][i - 1];   // R[i-1, j-1]
      const float bb = rbuf[c1][i - 1];  // R[i-1, j]
      const float cc = rbuf[c1][i];      // R[i, j-1]
      const float r = dv + softmin3(a, bb, cc);
      rbuf[c0][i] = r;
      Rb[(size_t)i * (MM + 1) + j] = r;
      last_r = r;
    } else {
      rbuf[c0][i] = BIGF;
    }
    if (t == 0) rbuf[c0][0] = BIGF;  // R[0, d] boundary
    __syncthreads();
    const int tmp = c2; c2 = c1; c1 = c0; c0 = tmp;
  }
  if (t == NN - 1) score[b] = last_r;  // R[N, M]
}

// Backward: Rbar[i,j] = seed + sum over successors of Rbar*exp(R_succ - R_ij - D_succ).
// E[b, i-1, j-1] = Rbar[i,j]. Reverse wavefront; D recomputed on the fly.
__global__ __launch_bounds__(1024) void sdtw_bwd_kernel(const float* __restrict__ x,
                                                        const float* __restrict__ y,
                                                        const float* __restrict__ R,
                                                        float* __restrict__ E) {
  __shared__ float ebuf[3][NN + 2];
  __shared__ float rbuf[3][NN + 2];
  const int b = blockIdx.x, t = threadIdx.x;
  const int i = t + 1;
  const float* Rb = R + (size_t)b * (NN + 1) * (MM + 1);
  float* Eb = E + (size_t)b * NN * MM;
  const float xi = x[b * NN + t];                       // x[b, i-1]
  const float xi1 = (i < NN) ? x[b * NN + i] : 0.0f;    // x[b, i] (for row i+1)
  for (int k = t; k < 3 * (NN + 2); k += 1024) {
    (&ebuf[0][0])[k] = 0.0f;
    (&rbuf[0][0])[k] = -BIGF;
  }
  __syncthreads();
  int cur = 0, nx1 = 1, nx2 = 2;  // d, d+1, d+2
  for (int d = NN + MM; d >= 2; --d) {
    if (i >= d - MM && i <= d - 1) {
      const int j = d - i;
      const float rij = Rb[(size_t)i * (MM + 1) + j];
      rbuf[cur][i] = rij;
      float acc = (i == NN && j == MM) ? 1.0f : 0.0f;
      const float yjm1 = y[j - 1];
      if (i + 1 <= NN) {  // successor (i+1, j): D = (x[i] - y[j-1])^2
        float dd = xi1 - yjm1; dd *= dd;
        acc += ebuf[nx1][i + 1] * expf(rbuf[nx1][i + 1] - rij - dd);
      }
      if (j + 1 <= MM) {
        const float yj = y[j];
        {  // successor (i, j+1): D = (x[i-1] - y[j])^2
          float dd = xi - yj; dd *= dd;
          acc += ebuf[nx1][i] * expf(rbuf[nx1][i] - rij - dd);
        }
        if (i + 1 <= NN) {  // successor (i+1, j+1): D = (x[i] - y[j])^2
          float dd = xi1 - yj; dd *= dd;
          acc += ebuf[nx2][i + 1] * expf(rbuf[nx2][i + 1] - rij - dd);
        }
      }
      ebuf[cur][i] = acc;
      Eb[(size_t)(i - 1) * MM + (j - 1)] = acc;
    } else {
      ebuf[cur][i] = 0.0f;
      rbuf[cur][i] = -BIGF;
    }
    __syncthreads();
    const int tmp = nx2; nx2 = nx1; nx1 = cur; cur = tmp;
  }
}

extern "C" void kernel_launch(void* const* d_in, const int* in_sizes, int n_in,
                              void* d_out, int out_size, void* d_ws, size_t ws_size,
                              hipStream_t stream) {
  const float* x = (const float*)d_in[0];  // [16, 1024]
  const float* y = (const float*)d_in[1];  // [1024]
  float* out = (float*)d_out;
  float* score = out;                                   // [16]
  float* D = out + NBATCH;                              // [16,1024,1024]
  float* R = D + (size_t)NBATCH * NN * MM;              // [16,1025,1025]
  float* E = R + (size_t)NBATCH * (NN + 1) * (MM + 1);  // [16,1024,1024]

  hipLaunchKernelGGL(d_init_kernel, dim3((NBATCH * NN * MM) / (256 * 4)), dim3(256), 0, stream,
                     x, y, D);
  hipLaunchKernelGGL(r_bound_kernel, dim3(NBATCH), dim3(1024), 0, stream, R);
  hipLaunchKernelGGL(sdtw_fwd_kernel, dim3(NBATCH), dim3(1024), 0, stream, x, y, R, score);
  hipLaunchKernelGGL(sdtw_bwd_kernel, dim3(NBATCH), dim3(1024), 0, stream, x, y, R, E);
}